// Round 1
// baseline (200.849 us; speedup 1.0000x reference)
//
#include <hip/hip_runtime.h>

// Problem constants: B=8, C=3, T=16, H=W=224, P0=2, P=16, FC=2
#define Bd 8
#define Cd 3
#define Td 16
#define Hd 224
#define Wd 224
#define Nd 1568                 // (T/2)*(H/16)*(W/16)
#define HWd (Hd*Wd)             // 50176
#define NPH 14                  // H/16
#define NPW 14                  // W/16
#define NT2 8                   // T/2
#define NSTRIP (Bd*NT2*NPH)     // 896 strips (b, t2, ph)
#define GRID_MAIN (NSTRIP*2)    // one block per (strip, i0) = 1792
#define HALO 2
#define SROWS (16 + 2*HALO)     // 20 staged rows
#define LROW 232                // padded LDS row (floats); 232 mod 32 = 8 -> 2-way max
#define LPLANE (SROWS*LROW)     // 4640 floats per channel plane
#define LDS_FLOATS (Cd*LPLANE)  // 13920 floats = 55680 B -> 2 blocks/CU
#define STG_TOTAL (Cd*SROWS*56) // 3360 float4 granules (56 per 224-wide row)
#define PATCH_ELEMS 1536.0

// ---------------- main: one block per (strip, time-slice) -----------------
// Stages [3][20][224] of raw (full-width strip + 2-row halo, perfectly
// coalesced contiguous slabs) into padded LDS, then computes all masked
// tokens of the strip. Horizontal gathers always hit LDS; vertical
// out-of-halo fallback (~0.3% of threads) goes to global.
__global__ __launch_bounds__(256)
void flow_mse_strip(const float* __restrict__ outp,
                    const float* __restrict__ raw,
                    const int* __restrict__ mask,
                    float* __restrict__ partial,
                    int* __restrict__ scnt) {
    __shared__ float lds[LDS_FLOATS];
    __shared__ unsigned smask;
    __shared__ float sred[4];

    const int tid   = threadIdx.x;
    const int bid   = blockIdx.x;
    const int strip = bid >> 1;
    const int i0    = bid & 1;
    const int b     = strip / (NT2 * NPH);          // /112
    const int sr    = strip - b * (NT2 * NPH);
    const int t2    = sr / NPH;
    const int ph    = sr - t2 * NPH;
    const int t     = (t2 << 1) | i0;
    const int ybase = (ph << 4) - HALO;

    // ---- stage phase 1: issue ALL global loads into registers (MLP) ----
    float4 rbuf[14];
    #pragma unroll
    for (int it = 0; it < 14; ++it) {
        int v = tid + (it << 8);
        if (v < STG_TOTAL) {
            int c    = v / 1120;                    // 20*56
            int rem  = v - c * 1120;
            int j    = rem / 56;
            int col4 = rem - j * 56;
            int y    = ybase + j;
            int yc   = min(max(y, 0), Hd - 1);      // clamp halo rows
            const float* g = raw + ((size_t)(b * Cd + c) * Td + t) * HWd
                           + yc * Wd + (col4 << 2);
            rbuf[it] = *(const float4*)g;
        }
    }

    // mask bits for this strip's 14 tokens (wave 0 only)
    const int nbase = t2 * 196 + ph * NPW;
    bool mm = false;
    if (tid < NPW) mm = (mask[b * Nd + nbase + tid] != 0);
    unsigned long long bal = __ballot(mm);
    if (tid == 0) smask = (unsigned)(bal & 0x3FFFull);

    // ---- stage phase 2: write registers to padded LDS ----
    #pragma unroll
    for (int it = 0; it < 14; ++it) {
        int v = tid + (it << 8);
        if (v < STG_TOTAL) {
            int c    = v / 1120;
            int rem  = v - c * 1120;
            int j    = rem / 56;
            int col4 = rem - j * 56;
            *(float4*)(lds + (c * SROWS + j) * LROW + (col4 << 2)) = rbuf[it];
        }
    }
    __syncthreads();

    unsigned mw = smask;
    float acc = 0.f;
    const int py = tid >> 4, px = tid & 15;
    const int h  = (ph << 4) + py;

    if (mw) {
        int pw = __ffs((int)mw) - 1;
        const float* fpf = outp + (((size_t)(b * Nd + nbase + pw)) << 10) + (i0 << 9);
        float2 f = ((const float2*)fpf)[tid];

        while (1) {
            unsigned nmw = mw & (mw - 1);
            int npw = 0;
            float2 nf = make_float2(0.f, 0.f);
            if (nmw) {                               // prefetch next token's flow
                npw = __ffs((int)nmw) - 1;
                const float* nfp = outp + (((size_t)(b * Nd + nbase + npw)) << 10) + (i0 << 9);
                nf = ((const float2*)nfp)[tid];
            }

            // ---- compute token pw ----
            {
                const int w = (pw << 4) + px;
                float mx = f.x + (float)w;
                float my = f.y + (float)h;
                float x0 = floorf(mx), y0 = floorf(my);
                float wx = mx - x0,    wy = my - y0;
                int x0i = (int)x0, y0i = (int)y0;
                int x1i = x0i + 1,  y1i = y0i + 1;

                bool vx0 = (x0i >= 0) && (x0i < Wd);
                bool vx1 = (x1i >= 0) && (x1i < Wd);
                bool vy0 = (y0i >= 0) && (y0i < Hd);
                bool vy1 = (y1i >= 0) && (y1i < Hd);

                float W00 = (1.f - wx) * (1.f - wy) * ((vx0 && vy0) ? 1.f : 0.f);
                float W01 = wx         * (1.f - wy) * ((vx1 && vy0) ? 1.f : 0.f);
                float W10 = (1.f - wx) * wy         * ((vx0 && vy1) ? 1.f : 0.f);
                float W11 = wx         * wy         * ((vx1 && vy1) ? 1.f : 0.f);

                int xc0 = min(max(x0i, 0), Wd - 1);
                int xc1 = min(max(x1i, 0), Wd - 1);
                int yc0 = min(max(y0i, 0), Hd - 1);
                int yc1 = min(max(y1i, 0), Hd - 1);
                int ly0 = yc0 - ybase, ly1 = yc1 - ybase;
                const int bt = (py + HALO) * LROW + w;   // target pixel (always staged)

                if ((ly0 >= 0) & (ly1 < SROWS)) {
                    const int b00 = ly0 * LROW + xc0;
                    const int b01 = ly0 * LROW + xc1;
                    const int b10 = ly1 * LROW + xc0;
                    const int b11 = ly1 * LROW + xc1;
                    #pragma unroll
                    for (int c = 0; c < Cd; ++c) {
                        const float* pl = lds + c * LPLANE;
                        float rec = pl[b00] * W00 + pl[b01] * W01
                                  + pl[b10] * W10 + pl[b11] * W11;
                        float d = rec - pl[bt];
                        acc += d * d;
                    }
                } else {                               // rare vertical out-of-halo
                    const int i00 = yc0 * Wd + xc0;
                    const int i01 = yc0 * Wd + xc1;
                    const int i10 = yc1 * Wd + xc0;
                    const int i11 = yc1 * Wd + xc1;
                    #pragma unroll
                    for (int c = 0; c < Cd; ++c) {
                        const float* img = raw + ((size_t)(b * Cd + c) * Td + t) * HWd;
                        float rec = img[i00] * W00 + img[i01] * W01
                                  + img[i10] * W10 + img[i11] * W11;
                        float d = rec - (lds + c * LPLANE)[bt];
                        acc += d * d;
                    }
                }
            }

            if (!nmw) break;
            mw = nmw; pw = npw; f = nf;
        }
    }

    // block reduce: 4 waves of 64
    for (int off = 32; off > 0; off >>= 1) acc += __shfl_down(acc, off, 64);
    if ((tid & 63) == 0) sred[tid >> 6] = acc;
    __syncthreads();
    if (tid == 0) {
        partial[bid] = sred[0] + sred[1] + sred[2] + sred[3];
        if (i0 == 0) scnt[strip] = __popc(smask);
    }
}

// ---------------- finalize: reduce partials + mask count -------------------
__global__ void finalize_kernel(const float* __restrict__ partial,
                                const int* __restrict__ scnt,
                                float* __restrict__ out) {
    const int tid = threadIdx.x;
    double s = 0.0;
    for (int i = tid; i < GRID_MAIN; i += 256) s += (double)partial[i];
    int c = 0;
    for (int i = tid; i < NSTRIP; i += 256) c += scnt[i];
    for (int off = 32; off > 0; off >>= 1) {
        s += __shfl_down(s, off, 64);
        c += __shfl_down(c, off, 64);
    }
    __shared__ double sd[4];
    __shared__ int    sc[4];
    int lane = tid & 63, wid = tid >> 6;
    if (lane == 0) { sd[wid] = s; sc[wid] = c; }
    __syncthreads();
    if (tid == 0) {
        double st = sd[0] + sd[1] + sd[2] + sd[3];
        int    ct = sc[0] + sc[1] + sc[2] + sc[3];
        double denom = (double)(ct > 0 ? ct : 1) * PATCH_ELEMS;
        out[0] = (float)(st / denom);
    }
}

extern "C" void kernel_launch(void* const* d_in, const int* in_sizes, int n_in,
                              void* d_out, int out_size, void* d_ws, size_t ws_size,
                              hipStream_t stream) {
    const float* outp = (const float*)d_in[0];   // (B,N,D) fp32 flow tokens
    const float* raw  = (const float*)d_in[1];   // (B,C,T,H,W) fp32
    const int*   mask = (const int*)d_in[2];     // (B,N)
    float* out = (float*)d_out;

    // ws layout: partial[GRID_MAIN] floats | scnt[NSTRIP] ints (all written
    // unconditionally -> no zero-init fills needed)
    float* partial = (float*)d_ws;
    int*   scnt    = (int*)((char*)d_ws + GRID_MAIN * 4);

    flow_mse_strip<<<GRID_MAIN, 256, 0, stream>>>(outp, raw, mask, partial, scnt);
    finalize_kernel<<<1, 256, 0, stream>>>(partial, scnt, out);
}

// Round 3
// 165.130 us; speedup vs baseline: 1.2163x; 1.2163x over previous
//
#include <hip/hip_runtime.h>

// Problem constants: B=8, C=3, T=16, H=W=224, P0=2, P=16, FC=2
#define Bd 8
#define Cd 3
#define Td 16
#define Hd 224
#define Wd 224
#define Nd 1568                 // (T/2)*(H/16)*(W/16)
#define HWd (Hd*Wd)             // 50176
#define NPH 14                  // H/16
#define NPW 14                  // W/16
#define NT2 8                   // T/2
#define NSTRIP (Bd*NT2*NPH)     // 896 strips (b, t2, ph)
#define GRID_MAIN (NSTRIP*2)    // one block per (strip, i0) = 1792
#define HALO 2
#define SROWS (16 + 2*HALO)     // 20 staged rows
#define LROW Wd                 // UNPADDED row: required for linear global_load_lds dest
#define LPLANE (SROWS*LROW)     // 4480 floats per channel plane
#define LDS_FLOATS (Cd*LPLANE)  // 13440 floats = 53760 B -> 3 blocks/CU
#define STG_GRAN (Cd*SROWS*56)  // 3360 16B granules (56 per 224-wide row)
#define PATCH_ELEMS 1536.0

typedef const float __attribute__((address_space(1))) gfloat;
typedef float __attribute__((address_space(3))) sfloat;

// ---------------- main: one block per (strip, time-slice) -----------------
// Stages [3][20][224] of raw (full-width strip + 2-row halo) into LDS via
// async global_load_lds (no VGPR round-trip, no spill), then computes all
// masked tokens of the strip. Horizontal gathers always hit LDS; vertical
// out-of-halo fallback (~5% of threads) goes to global (L2-resident strip).
__global__ __launch_bounds__(256)
void flow_mse_strip(const float* __restrict__ outp,
                    const float* __restrict__ raw,
                    const int* __restrict__ mask,
                    float* __restrict__ partial,
                    int* __restrict__ scnt) {
    __shared__ float lds[LDS_FLOATS];
    __shared__ float sred[4];

    const int tid   = threadIdx.x;
    const int bid   = blockIdx.x;
    const int strip = bid >> 1;
    const int i0    = bid & 1;
    const int b     = strip / (NT2 * NPH);          // /112
    const int sr    = strip - b * (NT2 * NPH);
    const int t2    = sr / NPH;
    const int ph    = sr - t2 * NPH;
    const int t     = (t2 << 1) | i0;
    const int ybase = (ph << 4) - HALO;

    // ---- async stage: 3360 16B granules, direct global->LDS ----
    // Per-lane GLOBAL addr (handles halo row clamp); LDS dest is linear in v,
    // i.e. wave-uniform base + lane*16B, matching HW semantics.
    const float* fbase = raw + ((size_t)b * Cd * Td + t) * HWd;
    #pragma unroll
    for (int it = 0; it < 14; ++it) {
        int v = tid + (it << 8);
        if (v < STG_GRAN) {
            int c    = v / 1120;                    // 20*56 granules per plane
            int rem  = v - c * 1120;
            int j    = rem / 56;
            int col4 = rem - j * 56;
            int yc   = min(max(ybase + j, 0), Hd - 1);
            const float* g = fbase + (size_t)c * (Td * HWd) + yc * Wd + (col4 << 2);
            __builtin_amdgcn_global_load_lds((gfloat*)g, (sfloat*)(lds + (v << 2)),
                                             16, 0, 0);
        }
    }

    // mask bits for this strip's 14 tokens: each wave ballots independently
    const int nbase = t2 * 196 + ph * NPW;
    const int lane  = tid & 63;
    bool mm = false;
    if (lane < NPW) mm = (mask[b * Nd + nbase + lane] != 0);
    const unsigned mw0   = (unsigned)(__ballot(mm) & 0x3FFFull);
    const int      tkcnt = __popc(mw0);             // preserved for denominator!

    __syncthreads();   // barrier drain waits vmcnt(0): staged data visible

    float acc = 0.f;
    const int py = tid >> 4, px = tid & 15;
    const int h  = (ph << 4) + py;

    unsigned mw = mw0;                              // scratch copy for iteration
    if (mw) {
        int pw = __ffs((int)mw) - 1;
        const float* fpf = outp + (((size_t)(b * Nd + nbase + pw)) << 10) + (i0 << 9);
        float2 f = ((const float2*)fpf)[tid];

        while (1) {
            unsigned nmw = mw & (mw - 1);
            int npw = 0;
            float2 nf = make_float2(0.f, 0.f);
            if (nmw) {                               // prefetch next token's flow
                npw = __ffs((int)nmw) - 1;
                const float* nfp = outp + (((size_t)(b * Nd + nbase + npw)) << 10) + (i0 << 9);
                nf = ((const float2*)nfp)[tid];
            }

            // ---- compute token pw ----
            {
                const int w = (pw << 4) + px;
                float mx = f.x + (float)w;
                float my = f.y + (float)h;
                float x0 = floorf(mx), y0 = floorf(my);
                float wx = mx - x0,    wy = my - y0;
                int x0i = (int)x0, y0i = (int)y0;
                int x1i = x0i + 1,  y1i = y0i + 1;

                bool vx0 = (x0i >= 0) && (x0i < Wd);
                bool vx1 = (x1i >= 0) && (x1i < Wd);
                bool vy0 = (y0i >= 0) && (y0i < Hd);
                bool vy1 = (y1i >= 0) && (y1i < Hd);

                float W00 = (1.f - wx) * (1.f - wy) * ((vx0 && vy0) ? 1.f : 0.f);
                float W01 = wx         * (1.f - wy) * ((vx1 && vy0) ? 1.f : 0.f);
                float W10 = (1.f - wx) * wy         * ((vx0 && vy1) ? 1.f : 0.f);
                float W11 = wx         * wy         * ((vx1 && vy1) ? 1.f : 0.f);

                int xc0 = min(max(x0i, 0), Wd - 1);
                int xc1 = min(max(x1i, 0), Wd - 1);
                int yc0 = min(max(y0i, 0), Hd - 1);
                int yc1 = min(max(y1i, 0), Hd - 1);
                int ly0 = yc0 - ybase, ly1 = yc1 - ybase;
                const int bt = (py + HALO) * LROW + w;   // target pixel (always staged)

                if ((ly0 >= 0) & (ly1 < SROWS)) {
                    const int b00 = ly0 * LROW + xc0;
                    const int b01 = ly0 * LROW + xc1;
                    const int b10 = ly1 * LROW + xc0;
                    const int b11 = ly1 * LROW + xc1;
                    #pragma unroll
                    for (int c = 0; c < Cd; ++c) {
                        const float* pl = lds + c * LPLANE;
                        float rec = pl[b00] * W00 + pl[b01] * W01
                                  + pl[b10] * W10 + pl[b11] * W11;
                        float d = rec - pl[bt];
                        acc += d * d;
                    }
                } else {                               // rare vertical out-of-halo
                    const int i00 = yc0 * Wd + xc0;
                    const int i01 = yc0 * Wd + xc1;
                    const int i10 = yc1 * Wd + xc0;
                    const int i11 = yc1 * Wd + xc1;
                    #pragma unroll
                    for (int c = 0; c < Cd; ++c) {
                        const float* img = fbase + (size_t)c * (Td * HWd);
                        float rec = img[i00] * W00 + img[i01] * W01
                                  + img[i10] * W10 + img[i11] * W11;
                        float d = rec - (lds + c * LPLANE)[bt];
                        acc += d * d;
                    }
                }
            }

            if (!nmw) break;
            mw = nmw; pw = npw; f = nf;
        }
    }

    // block reduce: 4 waves of 64
    for (int off = 32; off > 0; off >>= 1) acc += __shfl_down(acc, off, 64);
    if ((tid & 63) == 0) sred[tid >> 6] = acc;
    __syncthreads();
    if (tid == 0) {
        partial[bid] = sred[0] + sred[1] + sred[2] + sred[3];
        if (i0 == 0) scnt[strip] = tkcnt;            // intact count, not consumed mw
    }
}

// ---------------- finalize: reduce partials + mask count -------------------
__global__ void finalize_kernel(const float* __restrict__ partial,
                                const int* __restrict__ scnt,
                                float* __restrict__ out) {
    const int tid = threadIdx.x;
    double s = 0.0;
    for (int i = tid; i < GRID_MAIN; i += 256) s += (double)partial[i];
    int c = 0;
    for (int i = tid; i < NSTRIP; i += 256) c += scnt[i];
    for (int off = 32; off > 0; off >>= 1) {
        s += __shfl_down(s, off, 64);
        c += __shfl_down(c, off, 64);
    }
    __shared__ double sd[4];
    __shared__ int    sc[4];
    int lane = tid & 63, wid = tid >> 6;
    if (lane == 0) { sd[wid] = s; sc[wid] = c; }
    __syncthreads();
    if (tid == 0) {
        double st = sd[0] + sd[1] + sd[2] + sd[3];
        int    ct = sc[0] + sc[1] + sc[2] + sc[3];
        double denom = (double)(ct > 0 ? ct : 1) * PATCH_ELEMS;
        out[0] = (float)(st / denom);
    }
}

extern "C" void kernel_launch(void* const* d_in, const int* in_sizes, int n_in,
                              void* d_out, int out_size, void* d_ws, size_t ws_size,
                              hipStream_t stream) {
    const float* outp = (const float*)d_in[0];   // (B,N,D) fp32 flow tokens
    const float* raw  = (const float*)d_in[1];   // (B,C,T,H,W) fp32
    const int*   mask = (const int*)d_in[2];     // (B,N)
    float* out = (float*)d_out;

    // ws layout: partial[GRID_MAIN] floats | scnt[NSTRIP] ints (all written
    // unconditionally -> no zero-init fills needed)
    float* partial = (float*)d_ws;
    int*   scnt    = (int*)((char*)d_ws + GRID_MAIN * 4);

    flow_mse_strip<<<GRID_MAIN, 256, 0, stream>>>(outp, raw, mask, partial, scnt);
    finalize_kernel<<<1, 256, 0, stream>>>(partial, scnt, out);
}

// Round 4
// 160.335 us; speedup vs baseline: 1.2527x; 1.0299x over previous
//
#include <hip/hip_runtime.h>

// Problem constants: B=8, C=3, T=16, H=W=224, P0=2, P=16, FC=2
#define Bd 8
#define Cd 3
#define Td 16
#define Hd 224
#define Wd 224
#define Nd 1568                 // (T/2)*(H/16)*(W/16)
#define HWd (Hd*Wd)             // 50176
#define NPH 14                  // H/16
#define NPW 14                  // W/16
#define NT2 8                   // T/2
#define NSTRIP (Bd*NT2*NPH)     // 896 strips (b, t2, ph)
#define NUNIT (NSTRIP*2)        // 1792 (strip, i0) units
#define GRID_MAIN (NUNIT*3)     // 5376: one block per (unit, channel)
#define UPX (NUNIT/8)           // 224 units per XCD chunk
#define HALO 2
#define SROWS (16 + 2*HALO)     // 20 staged rows
#define LROW Wd                 // unpadded row: linear global_load_lds dest
#define LDS_FLOATS (SROWS*LROW) // 4480 floats = 17920 B -> 8 blocks/CU
#define STG_GRAN (SROWS*56)     // 1120 16B granules (56 per 224-wide row)
#define PATCH_ELEMS 1536.0

typedef const float __attribute__((address_space(1))) gfloat;
typedef float __attribute__((address_space(3))) sfloat;

// ---------------- main: one block per (strip, time-slice, channel) --------
// Channel-split for occupancy: 17.9 KB LDS + <=64 VGPR -> 8 blocks/CU
// (32 waves), vs 3 blocks in the monolithic version. Stage [20][224] of one
// channel plane via async global_load_lds, then compute all masked tokens.
// Grid is grouped so the 3 channel-blocks of a unit are adjacent on the
// same XCD (bid&7 round-robin) -> flow-token reads L2-hit 2 of 3 times.
__global__ __launch_bounds__(256, 8)
void flow_mse_strip(const float* __restrict__ outp,
                    const float* __restrict__ raw,
                    const int* __restrict__ mask,
                    float* __restrict__ partial,
                    int* __restrict__ scnt) {
    __shared__ float lds[LDS_FLOATS];
    __shared__ float sred[4];

    const int tid  = threadIdx.x;
    const int bid  = blockIdx.x;
    // XCD-grouped decode: xcd = bid&7 owns units [xcd*UPX, (xcd+1)*UPX);
    // its 3*UPX slots are (unit-local, channel) with channel innermost.
    const int xcd  = bid & 7;
    const int slot = bid >> 3;            // 0..671
    const int c    = slot % 3;
    const int ul   = slot / 3;            // 0..223
    const int u    = xcd * UPX + ul;      // 0..1791
    const int strip = u >> 1;
    const int i0    = u & 1;
    const int b     = strip / (NT2 * NPH);
    const int sr    = strip - b * (NT2 * NPH);
    const int t2    = sr / NPH;
    const int ph    = sr - t2 * NPH;
    const int t     = (t2 << 1) | i0;
    const int ybase = (ph << 4) - HALO;

    // ---- async stage: 1120 16B granules of one channel plane ----
    const float* plane = raw + ((size_t)(b * Cd + c) * Td + t) * HWd;
    #pragma unroll
    for (int it = 0; it < 5; ++it) {
        int v = tid + (it << 8);
        if (v < STG_GRAN) {
            int j    = v / 56;
            int col4 = v - j * 56;
            int yc   = min(max(ybase + j, 0), Hd - 1);
            const float* g = plane + yc * Wd + (col4 << 2);
            __builtin_amdgcn_global_load_lds((gfloat*)g, (sfloat*)(lds + (v << 2)),
                                             16, 0, 0);
        }
    }

    // mask bits for this strip's 14 tokens: per-wave ballot
    const int nbase = t2 * 196 + ph * NPW;
    const int lane  = tid & 63;
    bool mm = false;
    if (lane < NPW) mm = (mask[b * Nd + nbase + lane] != 0);
    const unsigned mw0   = (unsigned)(__ballot(mm) & 0x3FFFull);
    const int      tkcnt = __popc(mw0);

    __syncthreads();   // barrier drain waits vmcnt(0): staged data visible

    float acc = 0.f;
    const int py = tid >> 4, px = tid & 15;
    const int h  = (ph << 4) + py;
    const int bt = (py + HALO) * LROW;    // target row base (col added later)

    unsigned mw = mw0;
    while (mw) {
        const int pw = __ffs((int)mw) - 1;
        mw &= mw - 1;

        const float* fpf = outp + (((size_t)(b * Nd + nbase + pw)) << 10) + (i0 << 9);
        float2 f = ((const float2*)fpf)[tid];

        const int w = (pw << 4) + px;
        float mx = f.x + (float)w;
        float my = f.y + (float)h;
        float x0 = floorf(mx), y0 = floorf(my);
        float wx = mx - x0,    wy = my - y0;
        int x0i = (int)x0, y0i = (int)y0;
        int x1i = x0i + 1,  y1i = y0i + 1;

        bool vx0 = (x0i >= 0) && (x0i < Wd);
        bool vx1 = (x1i >= 0) && (x1i < Wd);
        bool vy0 = (y0i >= 0) && (y0i < Hd);
        bool vy1 = (y1i >= 0) && (y1i < Hd);

        float W00 = (1.f - wx) * (1.f - wy) * ((vx0 && vy0) ? 1.f : 0.f);
        float W01 = wx         * (1.f - wy) * ((vx1 && vy0) ? 1.f : 0.f);
        float W10 = (1.f - wx) * wy         * ((vx0 && vy1) ? 1.f : 0.f);
        float W11 = wx         * wy         * ((vx1 && vy1) ? 1.f : 0.f);

        int xc0 = min(max(x0i, 0), Wd - 1);
        int xc1 = min(max(x1i, 0), Wd - 1);
        int yc0 = min(max(y0i, 0), Hd - 1);
        int yc1 = min(max(y1i, 0), Hd - 1);
        int ly0 = yc0 - ybase, ly1 = yc1 - ybase;

        float tg = lds[bt + w];           // target pixel (always staged)
        float rec;
        if ((ly0 >= 0) & (ly1 < SROWS)) {
            rec = lds[ly0 * LROW + xc0] * W00 + lds[ly0 * LROW + xc1] * W01
                + lds[ly1 * LROW + xc0] * W10 + lds[ly1 * LROW + xc1] * W11;
        } else {                          // rare vertical out-of-halo
            rec = plane[yc0 * Wd + xc0] * W00 + plane[yc0 * Wd + xc1] * W01
                + plane[yc1 * Wd + xc0] * W10 + plane[yc1 * Wd + xc1] * W11;
        }
        float d = rec - tg;
        acc += d * d;
    }

    // block reduce: 4 waves of 64
    for (int off = 32; off > 0; off >>= 1) acc += __shfl_down(acc, off, 64);
    if ((tid & 63) == 0) sred[tid >> 6] = acc;
    __syncthreads();
    if (tid == 0) {
        partial[bid] = sred[0] + sred[1] + sred[2] + sred[3];
        if (c == 0 && i0 == 0) scnt[strip] = tkcnt;
    }
}

// ---------------- finalize: reduce partials + mask count -------------------
__global__ void finalize_kernel(const float* __restrict__ partial,
                                const int* __restrict__ scnt,
                                float* __restrict__ out) {
    const int tid = threadIdx.x;
    double s = 0.0;
    for (int i = tid; i < GRID_MAIN; i += 256) s += (double)partial[i];
    int c = 0;
    for (int i = tid; i < NSTRIP; i += 256) c += scnt[i];
    for (int off = 32; off > 0; off >>= 1) {
        s += __shfl_down(s, off, 64);
        c += __shfl_down(c, off, 64);
    }
    __shared__ double sd[4];
    __shared__ int    sc[4];
    int lane = tid & 63, wid = tid >> 6;
    if (lane == 0) { sd[wid] = s; sc[wid] = c; }
    __syncthreads();
    if (tid == 0) {
        double st = sd[0] + sd[1] + sd[2] + sd[3];
        int    ct = sc[0] + sc[1] + sc[2] + sc[3];
        double denom = (double)(ct > 0 ? ct : 1) * PATCH_ELEMS;
        out[0] = (float)(st / denom);
    }
}

extern "C" void kernel_launch(void* const* d_in, const int* in_sizes, int n_in,
                              void* d_out, int out_size, void* d_ws, size_t ws_size,
                              hipStream_t stream) {
    const float* outp = (const float*)d_in[0];   // (B,N,D) fp32 flow tokens
    const float* raw  = (const float*)d_in[1];   // (B,C,T,H,W) fp32
    const int*   mask = (const int*)d_in[2];     // (B,N)
    float* out = (float*)d_out;

    // ws layout: partial[GRID_MAIN] floats | scnt[NSTRIP] ints (all written
    // unconditionally -> no zero-init fills needed)
    float* partial = (float*)d_ws;
    int*   scnt    = (int*)((char*)d_ws + GRID_MAIN * 4);

    flow_mse_strip<<<GRID_MAIN, 256, 0, stream>>>(outp, raw, mask, partial, scnt);
    finalize_kernel<<<1, 256, 0, stream>>>(partial, scnt, out);
}